// Round 8
// baseline (190.249 us; speedup 1.0000x reference)
//
#include <hip/hip_runtime.h>

// DetectionLoss: B=32768, G=7, A=2, C=3, M=20.
// R10: test the LAST distinct read path. Evidence: preds reads flat at
// ~1.8 TB/s across R3/R6/R7/R8/R9 (scalar/float4, depth 1-4 verified, occ
// 9-100%, nt/cached, monolith/split) while fills write 6.8 TB/s -> flat
// per-CU return-path cap on VGPR-returning loads suspected (~7 GB/s/CU).
// det_loss_noobj now stages via __builtin_amdgcn_global_load_lds (TA->LDS
// DMA, no VGPR writeback; sustains >13 TB/s staging in GEMM per guide):
//   - 1568 blocks x 256 thr; block covers 4096 contiguous float4 chunks.
//   - 4 windows of 1024 chunks (16 KB), double-buffered LDS (32 KB).
//   - Each wave stages ITS OWN 4 KB (4 x 1 KB DMA) and consumes only that
//     -> NO barriers; per-wave counted s_waitcnt vmcnt(4) keeps next
//     window's DMA in flight (never drain to 0 mid-loop).
//   - rule #18: sched_barrier(0) after each asm waitcnt.
// assign (wave-per-batch, verified R8/R9) and reduce unchanged; reduce also
// handles any n4 remainder (0 in practice).

namespace {
constexpr int kG = 7;
constexpr int kA = 2;
constexpr int kM = 20;
constexpr int kCells = kG * kG * kA;     // 98
constexpr int kCh = 8;                   // 5 + C
constexpr int kWavesA = 8;               // waves per assign block (1 batch/wave)
constexpr int kBlockA = 64 * kWavesA;    // 512
constexpr int kBlockN = 256;             // noobj stream block (4 waves)
constexpr int kWinChunks = 1024;         // float4 chunks per window = 16 KB
constexpr int kNW = 4;                   // windows per block
constexpr int kChunksPerBlkN = kWinChunks * kNW;   // 4096 chunks = 64 KB
}

__device__ __forceinline__ float softplus_fast(float x) {
    // logaddexp(x,0); fast exp/log — absmax threshold leaves huge slack
    return fmaxf(x, 0.0f) + __logf(1.0f + __expf(-fabsf(x)));
}

// ---------------- Kernel A: wave-per-batch assignment + positives ----------------
__global__ __launch_bounds__(kBlockA) void det_loss_assign(
    const float* __restrict__ preds,
    const float4* __restrict__ tboxes4,
    const int* __restrict__ tlabels,
    const int* __restrict__ nobjs,
    const float* __restrict__ anchors,
    const float* __restrict__ cweights,
    float* __restrict__ partialA,  // SoA [5][NA]
    int B, int NA)
{
    __shared__ float s_red[kWavesA][5];

    const int tid  = threadIdx.x;
    const int wave = tid >> 6;
    const int m    = tid & 63;                     // lane; lanes 0..19 = targets
    const int wb   = blockIdx.x * kWavesA + wave;  // batch handled by this wave
    const bool active = (wb < B);

    const float a00 = anchors[0], a01 = anchors[1];
    const float a10 = anchors[2], a11 = anchors[3];

    int nob = 0;
    if (active && m == 0) nob = nobjs[wb];
    nob = __shfl(nob, 0, 64);

    // ---- per-lane target assignment ----
    int cell = -1;                                 // batch-local cell in [0,98)
    float4 tv = make_float4(0.f, 0.f, 0.f, 0.f);
    if (active && m < kM) {
        const float4 box = tboxes4[(size_t)wb * kM + m];
        const float x1 = box.x, y1 = box.y, x2 = box.z, y2 = box.w;
        const float cx = (x1 + x2) * 0.5f, cy = (y1 + y2) * 0.5f;
        const float w = x2 - x1, h = y2 - y1;
        if (w > 0.f && h > 0.f && m < nob) {
            const int gi = min(max((int)floorf(cy * (float)kG), 0), kG - 1);
            const int gj = min(max((int)floorf(cx * (float)kG), 0), kG - 1);
            const float wg = w * (float)kG, hg = h * (float)kG;
            const float i0 = fminf(wg, a00) * fminf(hg, a01);
            const float u0 = wg * hg + a00 * a01 - i0;
            const float r0 = i0 / (u0 + 1e-6f);
            const float i1 = fminf(wg, a10) * fminf(hg, a11);
            const float u1 = wg * hg + a10 * a11 - i1;
            const float r1 = i1 / (u1 + 1e-6f);
            const int a = (r1 > r0) ? 1 : 0;       // argmax, first-max wins
            const float aw = a ? a10 : a00;
            const float ah = a ? a11 : a01;
            tv.x = cx * (float)kG - (float)gj;
            tv.y = cy * (float)kG - (float)gi;
            tv.z = __logf(fmaxf(wg, 0.01f) / (aw + 1e-6f));
            tv.w = __logf(fmaxf(hg, 0.01f) / (ah + 1e-6f));
            cell = (gi * kG + gj) * kA + a;
        }
    }

    // ---- dedup: last-write-wins == lose if ANY later lane has same cell ----
    bool win = (cell >= 0);
    #pragma unroll
    for (int s = 1; s < kM; ++s) {
        const int other = __shfl_down(cell, s, 64);
        if ((m + s < kM) && (cell >= 0) && (other == cell)) win = false;
    }
    const unsigned long long bal = __ballot(win);   // num_pos = popcount

    // ---- winner lanes: gather 32B preds cell + label, compute terms ----
    float accO = 0.f, accN = 0.f, accB = 0.f, accC = 0.f;
    if (win) {
        const float4* pc = (const float4*)(preds + ((size_t)wb * kCells + cell) * kCh);
        const float4 p0 = pc[0];
        const float4 p1 = pc[1];
        const float spp = softplus_fast(p0.x);
        accN -= spp;            // remove noobj term the stream kernel adds
        accO += spp - p0.x;     // softplus(-x) == softplus(x) - x
        float d, ad;
        d = p0.y - tv.x; ad = fabsf(d); accB += (ad < 1.f) ? 0.5f * d * d : ad - 0.5f;
        d = p0.z - tv.y; ad = fabsf(d); accB += (ad < 1.f) ? 0.5f * d * d : ad - 0.5f;
        d = p0.w - tv.z; ad = fabsf(d); accB += (ad < 1.f) ? 0.5f * d * d : ad - 0.5f;
        d = p1.x - tv.w; ad = fabsf(d); accB += (ad < 1.f) ? 0.5f * d * d : ad - 0.5f;
        const int lab = tlabels[(size_t)wb * kM + m];
        const float c0 = p1.y, c1 = p1.z, c2 = p1.w;
        const float mx = fmaxf(c0, fmaxf(c1, c2));
        const float lse = mx + __logf(__expf(c0 - mx) + __expf(c1 - mx) + __expf(c2 - mx));
        const float logit = (lab == 0) ? c0 : ((lab == 1) ? c1 : c2);
        accC += cweights[lab] * (lse - logit);
    }

    // ---- wave reduce (4 sums) ----
    float vals[4] = {accO, accN, accB, accC};
    #pragma unroll
    for (int k = 0; k < 4; ++k) {
        float v = vals[k];
        #pragma unroll
        for (int off = 32; off > 0; off >>= 1) v += __shfl_down(v, off, 64);
        vals[k] = v;
    }
    if (m == 0) {
        #pragma unroll
        for (int k = 0; k < 4; ++k) s_red[wave][k] = vals[k];
        s_red[wave][4] = (float)__popcll(bal);
    }
    __syncthreads();

    if (tid == 0) {
        float t[5];
        #pragma unroll
        for (int k = 0; k < 5; ++k) {
            float s = 0.f;
            #pragma unroll
            for (int w = 0; w < kWavesA; ++w) s += s_red[w][k];
            t[k] = s;
        }
        #pragma unroll
        for (int k = 0; k < 5; ++k)
            partialA[(size_t)k * NA + blockIdx.x] = t[k];
    }
}

// ---------------- Kernel B: LDS-DMA noobj stream ----------------
// Block covers chunks [blockIdx.x*4096, +4096). Per window (1024 chunks):
// wave wv stages its 256-chunk region with 4 global_load_lds (1 KB each:
// wave-uniform LDS base + lane*16, per-lane global addr) then consumes only
// that region -> no __syncthreads anywhere in the loop.
__global__ __launch_bounds__(kBlockN) void det_loss_noobj(
    const float4* __restrict__ preds4,
    float* __restrict__ partialN)   // [gridDim.x]
{
    __shared__ float4 sbuf[2][kWinChunks];
    __shared__ float s_red[kBlockN / 64];
    const int tid = threadIdx.x;
    const int wv  = tid >> 6;
    const int ln  = tid & 63;
    const long long g0 = (long long)blockIdx.x * kChunksPerBlkN;

    #define STAGE(DB, W)                                                        \
        {                                                                       \
            const long long base_ = g0 + (long long)(W) * kWinChunks + wv * 256 + ln; \
            _Pragma("unroll")                                                   \
            for (int c_ = 0; c_ < 4; ++c_) {                                    \
                __builtin_amdgcn_global_load_lds(                               \
                    (const __attribute__((address_space(1))) void*)(preds4 + base_ + c_ * 64), \
                    (__attribute__((address_space(3))) void*)&sbuf[(DB)][wv * 256 + c_ * 64], \
                    16, 0, 0);                                                  \
            }                                                                   \
        }

    float acc = 0.f;
    STAGE(0, 0)
    #pragma unroll
    for (int w = 0; w < kNW; ++w) {
        const int db = w & 1;
        if (w + 1 < kNW) {
            STAGE((w + 1) & 1, w + 1)
            asm volatile("s_waitcnt vmcnt(4)" ::: "memory");
        } else {
            asm volatile("s_waitcnt vmcnt(0)" ::: "memory");
        }
        __builtin_amdgcn_sched_barrier(0);
        // consume own region: even chunks' .x are obj logits (128 per wave)
        const float o0 = sbuf[db][wv * 256 + 2 * ln].x;
        const float o1 = sbuf[db][wv * 256 + 2 * ln + 128].x;
        acc += softplus_fast(o0) + softplus_fast(o1);
        __builtin_amdgcn_sched_barrier(0);   // keep reads inside this phase
    }
    #undef STAGE

    #pragma unroll
    for (int off = 32; off > 0; off >>= 1) acc += __shfl_down(acc, off, 64);
    if (ln == 0) s_red[wv] = acc;
    __syncthreads();
    if (tid == 0) {
        float t = 0.f;
        #pragma unroll
        for (int w = 0; w < kBlockN / 64; ++w) t += s_red[w];
        partialN[blockIdx.x] = t;
    }
}

// ---------------- Reduce (+ n4 remainder, 0 in practice) ----------------
__global__ __launch_bounds__(256) void det_loss_reduce(
    const float* __restrict__ partialA, int NA,
    const float* __restrict__ partialN, int NN,
    const float4* __restrict__ preds4, long long remStart, long long n4,
    float* __restrict__ out)
{
    __shared__ float s_red[4][5];
    const int tid = threadIdx.x;
    float v[5] = {0.f, 0.f, 0.f, 0.f, 0.f};
    for (int i = tid; i < NA; i += 256) {
        #pragma unroll
        for (int k = 0; k < 5; ++k) v[k] += partialA[(size_t)k * NA + i];
    }
    for (int i = tid; i < NN; i += 256) v[1] += partialN[i];
    for (long long i = remStart + 2 * tid; i < n4; i += 512)   // even chunks only
        v[1] += softplus_fast(preds4[i].x);
    #pragma unroll
    for (int k = 0; k < 5; ++k) {
        float x = v[k];
        #pragma unroll
        for (int off = 32; off > 0; off >>= 1) x += __shfl_down(x, off, 64);
        v[k] = x;
    }
    const int wave = tid >> 6;
    const int lane = tid & 63;
    if (lane == 0) {
        #pragma unroll
        for (int k = 0; k < 5; ++k) s_red[wave][k] = v[k];
    }
    __syncthreads();
    if (tid == 0) {
        float t[5];
        #pragma unroll
        for (int k = 0; k < 5; ++k) {
            float s = 0.f;
            #pragma unroll
            for (int w = 0; w < 4; ++w) s += s_red[w][k];
            t[k] = s;
        }
        const float npv = fmaxf(t[4], 1.0f);
        out[0] = (5.0f * t[2] + 1.0f * t[0] + 0.5f * t[1] + 2.0f * t[3]) / npv;
    }
}

extern "C" void kernel_launch(void* const* d_in, const int* in_sizes, int n_in,
                              void* d_out, int out_size, void* d_ws, size_t ws_size,
                              hipStream_t stream) {
    const float* preds    = (const float*)d_in[0];
    const float* tboxes   = (const float*)d_in[1];
    const int*   tlabels  = (const int*)d_in[2];
    const int*   nobjs    = (const int*)d_in[3];
    const float* anchors  = (const float*)d_in[4];
    const float* cweights = (const float*)d_in[5];
    float* out = (float*)d_out;

    const int B = in_sizes[0] / (kCells * kCh);   // /784
    const int blocksA = (B + kWavesA - 1) / kWavesA;              // 4096
    const long long n4 = (long long)B * kCells * 2;               // 6,422,528
    const int blocksN = (int)(n4 / kChunksPerBlkN);               // 1568 (exact)
    const long long remStart = (long long)blocksN * kChunksPerBlkN;

    float* partialA = (float*)d_ws;                    // [5][blocksA]
    float* partialN = partialA + (size_t)5 * blocksA;  // [blocksN]

    det_loss_assign<<<blocksA, kBlockA, 0, stream>>>(
        preds, (const float4*)tboxes, tlabels, nobjs, anchors, cweights,
        partialA, B, blocksA);
    if (blocksN > 0)
        det_loss_noobj<<<blocksN, kBlockN, 0, stream>>>(
            (const float4*)preds, partialN);
    det_loss_reduce<<<1, 256, 0, stream>>>(
        partialA, blocksA, partialN, blocksN,
        (const float4*)preds, remStart, n4, out);
}

// Round 9
// 183.829 us; speedup vs baseline: 1.0349x; 1.0349x over previous
//
#include <hip/hip_runtime.h>

// DetectionLoss: B=32768, G=7, A=2, C=3, M=20.
// R11 == R6 verbatim (best measured: 184.55us total, main 60.8us) — final
// lock-in at the characterized roofline.
// Roofline evidence (R3..R10): preds-stream reads pin at ~1.7-1.8 TB/s across
// six structures x two HW return paths (VGPR-return loads: scalar/float4/nt/
// deep-MLP; global_load_lds DMA), occupancy 9-100%, while HBM is 85% idle and
// poison-fills write 6.8 TB/s. Model: per-CU outstanding-read-line concurrency
// cap (~2.6KB lines in flight/CU at ~900cyc miss latency) shared by both read
// paths. All 103MB must transit (obj logits are 2-per-64B line -> no byte
// reduction). Floor = 103MB/1.8TB/s ~= 57us + reduce ~3us + 120.5us fixed
// harness fills ~= 181us; this config measures 184.6 (within ~2%).
// Monolith beats splits (R7-R10 +2..6us): assignment/dedup/positives hide
// inside the stream's latency slack (why R3==R6 despite opposite patterns).

namespace {
constexpr int kG = 7;
constexpr int kA = 2;
constexpr int kM = 20;
constexpr int kCells = kG * kG * kA;     // 98
constexpr int kCh = 8;                   // 5 + C
constexpr int kNB = 32;                  // batches per block
constexpr int kBlock = 448;              // 7 waves
constexpr int kTgt = kNB * kM;           // 640
constexpr int kChunks = kNB * kCells * 2;          // 6272 float4 chunks/block
constexpr int kIters = kChunks / kBlock;           // 14 exactly
}

__device__ __forceinline__ float softplus_fast(float x) {
    // logaddexp(x,0); fast exp/log — absmax threshold leaves huge slack
    return fmaxf(x, 0.0f) + __logf(1.0f + __expf(-fabsf(x)));
}

__global__ __launch_bounds__(kBlock) void det_loss_main(
    const float* __restrict__ preds,
    const float* __restrict__ tboxes,
    const int* __restrict__ tlabels,
    const int* __restrict__ nobjs,
    const float* __restrict__ anchors,
    const float* __restrict__ cweights,
    float* __restrict__ partial,   // SoA [5][gridDim.x]: obj, noobj, bbox, cls, npos
    int B)
{
    __shared__ float4 s_tv[kTgt];        // per-target (tx,ty,tw,th)
    __shared__ short  s_cell[kTgt];      // block-local cell = bl*98+c, -1 invalid
    __shared__ int    s_pos[kTgt];       // compacted winners: (j<<16)|cell
    __shared__ int    s_nobj[kNB];
    __shared__ int    s_npos;
    __shared__ float  s_red[kBlock / 64][4];

    const int tid = threadIdx.x;
    const int b0 = blockIdx.x * kNB;

    if (tid < kNB) {
        const int b = b0 + tid;
        s_nobj[tid] = (b < B) ? nobjs[b] : 0;
    }
    if (tid == 0) s_npos = 0;
    __syncthreads();

    const float a00 = anchors[0], a01 = anchors[1];
    const float a10 = anchors[2], a11 = anchors[3];

    // ---- Phase 1: per-target assignment ----
    for (int j = tid; j < kTgt; j += kBlock) {
        const int bl = j / kM;
        const int m  = j - bl * kM;
        short cell = -1;
        float4 tv = make_float4(0.f, 0.f, 0.f, 0.f);
        if (b0 + bl < B) {
            const float4 box = ((const float4*)tboxes)[(size_t)b0 * kM + j];
            const float x1 = box.x, y1 = box.y, x2 = box.z, y2 = box.w;
            const float cx = (x1 + x2) * 0.5f, cy = (y1 + y2) * 0.5f;
            const float w = x2 - x1, h = y2 - y1;
            if (w > 0.f && h > 0.f && m < s_nobj[bl]) {
                const int gi = min(max((int)floorf(cy * (float)kG), 0), kG - 1);
                const int gj = min(max((int)floorf(cx * (float)kG), 0), kG - 1);
                const float wg = w * (float)kG, hg = h * (float)kG;
                const float i0 = fminf(wg, a00) * fminf(hg, a01);
                const float u0 = wg * hg + a00 * a01 - i0;
                const float r0 = i0 / (u0 + 1e-6f);
                const float i1 = fminf(wg, a10) * fminf(hg, a11);
                const float u1 = wg * hg + a10 * a11 - i1;
                const float r1 = i1 / (u1 + 1e-6f);
                const int a = (r1 > r0) ? 1 : 0;   // argmax, first-max wins
                const float aw = a ? a10 : a00;
                const float ah = a ? a11 : a01;
                tv.x = cx * (float)kG - (float)gj;
                tv.y = cy * (float)kG - (float)gi;
                tv.z = __logf(fmaxf(wg, 0.01f) / (aw + 1e-6f));
                tv.w = __logf(fmaxf(hg, 0.01f) / (ah + 1e-6f));
                cell = (short)(bl * kCells + (gi * kG + gj) * kA + a);
            }
        }
        s_cell[j] = cell;
        s_tv[j] = tv;
    }
    __syncthreads();

    // ---- Phase 1b: dedup (last-write-wins) + compaction ----
    for (int j = tid; j < kTgt; j += kBlock) {
        const short c = s_cell[j];
        if (c >= 0) {
            const int bl = j / kM;
            const int m  = j - bl * kM;
            bool win = true;
            for (int m2 = m + 1; m2 < kM; ++m2) {
                if (s_cell[bl * kM + m2] == c) { win = false; break; }
            }
            if (win) {
                const int idx = atomicAdd(&s_npos, 1);
                s_pos[idx] = (j << 16) | (int)c;
            }
        }
    }
    __syncthreads();

    // ---- Phase 2: fully-coalesced float4 stream of the whole preds block ----
    // Chunk c (16B) covers cell c/2; even chunks hold (obj, bx, by, bw).
    // tid + k*kBlock preserves parity (kBlock even) -> even threads always see
    // obj-bearing chunks; odd threads contribute nothing (predicated VALU).
    float accO = 0.f, accN = 0.f, accB = 0.f, accC = 0.f;
    const float* __restrict__ pblk = preds + (size_t)b0 * kCells * kCh;
    const float4* __restrict__ pblk4 = (const float4*)pblk;
    if (b0 + kNB <= B) {
        const bool hasObj = (tid & 1) == 0;
        #pragma unroll
        for (int k = 0; k < kIters; ++k) {
            const float4 v = pblk4[(size_t)(tid + k * kBlock)];
            if (hasObj) accN += softplus_fast(v.x);
        }
    } else {
        const int nchunk = (B - b0) * kCells * 2;
        const bool hasObj = (tid & 1) == 0;
        for (int i = tid; i < nchunk; i += kBlock) {
            const float4 v = pblk4[(size_t)i];
            if (hasObj) accN += softplus_fast(v.x);
        }
    }

    // ---- Phase 2b: compacted positives ----
    const int np = s_npos;
    const float cw0 = cweights[0], cw1 = cweights[1], cw2 = cweights[2];
    for (int t = tid; t < np; t += kBlock) {
        const int pk = s_pos[t];
        const int j  = pk >> 16;
        const int ci = pk & 0xFFFF;
        const float4* pc = (const float4*)(pblk + (size_t)ci * kCh);
        const float4 p0 = pc[0];
        const float4 p1 = pc[1];
        const float spp = softplus_fast(p0.x);
        accN -= spp;            // remove wrongly-added noobj term
        accO += spp - p0.x;     // softplus(-x) == softplus(x) - x
        const float4 tv = s_tv[j];
        float d, ad;
        d = p0.y - tv.x; ad = fabsf(d); accB += (ad < 1.f) ? 0.5f * d * d : ad - 0.5f;
        d = p0.z - tv.y; ad = fabsf(d); accB += (ad < 1.f) ? 0.5f * d * d : ad - 0.5f;
        d = p0.w - tv.z; ad = fabsf(d); accB += (ad < 1.f) ? 0.5f * d * d : ad - 0.5f;
        d = p1.x - tv.w; ad = fabsf(d); accB += (ad < 1.f) ? 0.5f * d * d : ad - 0.5f;
        const int lab = tlabels[(size_t)b0 * kM + j];
        const float c0 = p1.y, c1 = p1.z, c2 = p1.w;
        const float mx = fmaxf(c0, fmaxf(c1, c2));
        const float lse = mx + __logf(__expf(c0 - mx) + __expf(c1 - mx) + __expf(c2 - mx));
        const float logit = (lab == 0) ? c0 : ((lab == 1) ? c1 : c2);
        const float cwv   = (lab == 0) ? cw0 : ((lab == 1) ? cw1 : cw2);
        accC += cwv * (lse - logit);
    }

    // ---- Block reduce (4 float sums) + plain SoA stores ----
    float vals[4] = {accO, accN, accB, accC};
    #pragma unroll
    for (int k = 0; k < 4; ++k) {
        float v = vals[k];
        #pragma unroll
        for (int off = 32; off > 0; off >>= 1) v += __shfl_down(v, off, 64);
        vals[k] = v;
    }
    const int wave = tid >> 6;
    const int lane = tid & 63;
    if (lane == 0) {
        #pragma unroll
        for (int k = 0; k < 4; ++k) s_red[wave][k] = vals[k];
    }
    __syncthreads();
    if (tid == 0) {
        const int nb = gridDim.x;
        #pragma unroll
        for (int k = 0; k < 4; ++k) {
            float t = 0.f;
            #pragma unroll
            for (int w = 0; w < kBlock / 64; ++w) t += s_red[w][k];
            partial[(size_t)k * nb + blockIdx.x] = t;
        }
        partial[(size_t)4 * nb + blockIdx.x] = (float)np;   // num_pos
    }
}

__global__ __launch_bounds__(256) void det_loss_reduce(
    const float* __restrict__ partial, int nblocks, float* __restrict__ out)
{
    __shared__ float s_red[4][5];
    const int tid = threadIdx.x;
    float v[5] = {0.f, 0.f, 0.f, 0.f, 0.f};
    for (int i = tid; i < nblocks; i += 256) {
        #pragma unroll
        for (int k = 0; k < 5; ++k) v[k] += partial[(size_t)k * nblocks + i];
    }
    #pragma unroll
    for (int k = 0; k < 5; ++k) {
        float x = v[k];
        #pragma unroll
        for (int off = 32; off > 0; off >>= 1) x += __shfl_down(x, off, 64);
        v[k] = x;
    }
    const int wave = tid >> 6;
    const int lane = tid & 63;
    if (lane == 0) {
        #pragma unroll
        for (int k = 0; k < 5; ++k) s_red[wave][k] = v[k];
    }
    __syncthreads();
    if (tid == 0) {
        float t[5];
        #pragma unroll
        for (int k = 0; k < 5; ++k) {
            float s = 0.f;
            #pragma unroll
            for (int w = 0; w < 4; ++w) s += s_red[w][k];
            t[k] = s;
        }
        const float npv = fmaxf(t[4], 1.0f);
        out[0] = (5.0f * t[2] + 1.0f * t[0] + 0.5f * t[1] + 2.0f * t[3]) / npv;
    }
}

extern "C" void kernel_launch(void* const* d_in, const int* in_sizes, int n_in,
                              void* d_out, int out_size, void* d_ws, size_t ws_size,
                              hipStream_t stream) {
    const float* preds    = (const float*)d_in[0];
    const float* tboxes   = (const float*)d_in[1];
    const int*   tlabels  = (const int*)d_in[2];
    const int*   nobjs    = (const int*)d_in[3];
    const float* anchors  = (const float*)d_in[4];
    const float* cweights = (const float*)d_in[5];
    float* out = (float*)d_out;
    float* partial = (float*)d_ws;   // [5][nblocks], fully overwritten every call

    const int B = in_sizes[0] / (kCells * kCh);   // /784
    const int blocks = (B + kNB - 1) / kNB;

    det_loss_main<<<blocks, kBlock, 0, stream>>>(
        preds, tboxes, tlabels, nobjs, anchors, cweights, partial, B);
    det_loss_reduce<<<1, 256, 0, stream>>>(partial, blocks, out);
}